// Round 4
// baseline (560.371 us; speedup 1.0000x reference)
//
#include <hip/hip_runtime.h>

#define NN 20000      // nodes
#define NNP 20032     // padded rows (64-row GEMM tiles read past NN)
#define NH 128        // hidden
#define NG 64         // graphs
#define NLAY 3
#define NCH 5         // 4 splits + main
#define GEPS 1e-5f
#define GSLOPE 0.01f

typedef unsigned short u16;
typedef unsigned int u32;
typedef __attribute__((ext_vector_type(8))) short short8;
typedef __attribute__((ext_vector_type(4))) float float4v;

__device__ __forceinline__ u16 f2bf(float f) {
  union { float f; u32 u; } v; v.f = f;
  u32 r = (v.u + 0x7fffu + ((v.u >> 16) & 1u)) >> 16;
  return (u16)r;
}
__device__ __forceinline__ float bf2f(u16 u) { return __uint_as_float((u32)u << 16); }

struct ZP {
  const u16* A[NCH];     // GEMM input (bf16, NNP rows)
  const u16* W[NCH];     // GEMM weight, bf16 transposed [N][K]
  u16* Y[NCH];           // GEMM output / gather source (bf16)
  u16* Xo[NCH];          // post-agg pre-norm (bf16)
  u16* Xn[NCH];          // post-norm, next layer's A (bf16, NNP rows)
  const float* bias[NCH];
  const float* gw[NCH];
  const float* gb[NCH];
  const float* gms[NCH];
  int set[NCH];
  int colbase[NCH];
};

struct ES4 {
  const int* e[4];
  int cnt[4];
  int off[4];
};

// ---------------- setup kernels ----------------

// batch is sorted -> per-graph start/count via binary search, no atomics
__global__ void k_count2(const int* __restrict__ batch, int* __restrict__ counts,
                         int* __restrict__ gstart) {
  int g = threadIdx.x;
  if (g >= NG) return;
  auto lb = [&](int key) {
    int lo = 0, hi = NN;
    while (lo < hi) {
      int mid = (lo + hi) >> 1;
      if (batch[mid] < key) lo = mid + 1; else hi = mid;
    }
    return lo;
  };
  int a = lb(g), b = lb(g + 1);
  gstart[g] = a;
  counts[g] = b - a;
}

__global__ void k_deg(ES4 es, int* __restrict__ deg) {
  int s = blockIdx.y;
  int i = blockIdx.x * 256 + threadIdx.x;
  int E = es.cnt[s];
  if (i < E) atomicAdd(&deg[s * NN + es.e[s][E + i]], 1);
}

// exclusive scan of deg -> indptr (+cursor copy) and dinv = rsqrt(deg+1) fused
__global__ void k_scan(const int* __restrict__ deg, int* __restrict__ indptr,
                       int* __restrict__ cursor, float* __restrict__ dinv) {
  int s = blockIdx.x;
  const int* d = deg + s * NN;
  int* ip = indptr + s * (NN + 1);
  int* cu = cursor + s * (NN + 1);
  __shared__ int part[1024];
  int t = threadIdx.x;
  const int CH = (NN + 1023) / 1024;
  int base = t * CH;
  int sum = 0;
  for (int j = 0; j < CH; j++) {
    int idx = base + j;
    if (idx < NN) {
      int dv = d[idx];
      sum += dv;
      dinv[s * NN + idx] = rsqrtf((float)dv + 1.0f);
    }
  }
  part[t] = sum;
  __syncthreads();
  for (int off = 1; off < 1024; off <<= 1) {
    int v = part[t];
    int u = (t >= off) ? part[t - off] : 0;
    __syncthreads();
    part[t] = v + u;
    __syncthreads();
  }
  int run = (t == 0) ? 0 : part[t - 1];
  for (int j = 0; j < CH; j++) {
    int idx = base + j;
    if (idx < NN) { ip[idx] = run; cu[idx] = run; run += d[idx]; }
  }
  if (t == 1023) { ip[NN] = run; cu[NN] = run; }
}

__global__ void k_fill(ES4 es, const float* __restrict__ dinv, int* __restrict__ cursor,
                       int2* __restrict__ ent) {
  int s = blockIdx.y;
  int i = blockIdx.x * 256 + threadIdx.x;
  int E = es.cnt[s];
  if (i >= E) return;
  int src = es.e[s][i];
  int dst = es.e[s][E + i];
  int pos = atomicAdd(&cursor[s * (NN + 1) + dst], 1);
  float c = dinv[s * NN + src] * dinv[s * NN + dst];
  ent[es.off[s] + pos] = make_int2(src, __float_as_int(c));
}

// weights: fp32 [K][N] -> bf16 transposed [N][K]; mats: 0=emb, 1-3=loc, 4-6=main
__global__ void k_prepw(const float* __restrict__ embW, const float* __restrict__ locW,
                        const float* __restrict__ mainW, u16* __restrict__ wt) {
  int mat = blockIdx.y;
  int n = blockIdx.x;
  int k = threadIdx.x;
  const float* W = (mat == 0) ? embW : ((mat <= 3) ? locW + (mat - 1) * NH * NH
                                                   : mainW + (mat - 4) * NH * NH);
  wt[(size_t)mat * NH * NH + n * NH + k] = f2bf(W[(size_t)k * NH + n]);
}

__global__ void k_cast(const float* __restrict__ x, u16* __restrict__ xb) {
  int i = (blockIdx.x * 256 + threadIdx.x) * 8;
  if (i >= NN * NH) return;
  float4 a = *(const float4*)(x + i);
  float4 b = *(const float4*)(x + i + 4);
  uint4 o;
  o.x = f2bf(a.x) | ((u32)f2bf(a.y) << 16);
  o.y = f2bf(a.z) | ((u32)f2bf(a.w) << 16);
  o.z = f2bf(b.x) | ((u32)f2bf(b.y) << 16);
  o.w = f2bf(b.z) | ((u32)f2bf(b.w) << 16);
  *(uint4*)(xb + i) = o;
}

// ---------------- compute kernels ----------------

// Y[z] = A[z] @ Wt[z]^T (+gbias). bf16 MFMA 16x16x32, 64-row tile, K=128 in LDS.
__global__ __launch_bounds__(256) void k_gemm_bf(ZP p, const float* __restrict__ gbias) {
  int zi = blockIdx.y;
  const u16* __restrict__ A = p.A[zi];
  const u16* __restrict__ Wt = p.W[zi];
  u16* __restrict__ Y = p.Y[zi];
  __shared__ u16 As[64][136];   // +8 pad: 2-way bank aliasing only
  __shared__ u16 Bs[128][136];
  int t = threadIdx.x;
  int row0 = blockIdx.x * 64;
  int c = t & 15, rs = t >> 4;
#pragma unroll
  for (int pass = 0; pass < 4; pass++) {
    int r = pass * 16 + rs;
    *(uint4*)(&As[r][c * 8]) = *(const uint4*)(A + (size_t)(row0 + r) * NH + c * 8);
  }
#pragma unroll
  for (int pass = 0; pass < 8; pass++) {
    int n = pass * 16 + rs;
    *(uint4*)(&Bs[n][c * 8]) = *(const uint4*)(Wt + (size_t)n * NH + c * 8);
  }
  __syncthreads();
  int lane = t & 63, w = t >> 6;
  int m16 = lane & 15, quad = lane >> 4;
  float4v acc[8];
#pragma unroll
  for (int i = 0; i < 8; i++) acc[i] = (float4v)(0.f);
#pragma unroll
  for (int kk = 0; kk < 4; kk++) {
    short8 av = *(const short8*)(&As[w * 16 + m16][kk * 32 + quad * 8]);
#pragma unroll
    for (int ct = 0; ct < 8; ct++) {
      short8 bv = *(const short8*)(&Bs[ct * 16 + m16][kk * 32 + quad * 8]);
      acc[ct] = __builtin_amdgcn_mfma_f32_16x16x32_bf16(av, bv, acc[ct], 0, 0, 0);
    }
  }
  __syncthreads();
  // epilogue: C/D layout col=lane&15, row=quad*4+reg -> LDS bounce -> 16B stores
#pragma unroll
  for (int ct = 0; ct < 8; ct++) {
    float bv = gbias ? gbias[ct * 16 + m16] : 0.f;
#pragma unroll
    for (int r = 0; r < 4; r++) {
      As[w * 16 + quad * 4 + r][ct * 16 + m16] = f2bf(acc[ct][r] + bv);
    }
  }
  __syncthreads();
#pragma unroll
  for (int pass = 0; pass < 4; pass++) {
    int r = pass * 16 + rs;
    int gr = row0 + r;
    if (gr < NN) *(uint4*)(Y + (size_t)gr * NH + c * 8) = *(const uint4*)(&As[r][c * 8]);
  }
}

__device__ __forceinline__ void fma8(float* a, uint4 v, float cf) {
  a[0] += cf * __uint_as_float(v.x << 16);
  a[1] += cf * __uint_as_float(v.x & 0xffff0000u);
  a[2] += cf * __uint_as_float(v.y << 16);
  a[3] += cf * __uint_as_float(v.y & 0xffff0000u);
  a[4] += cf * __uint_as_float(v.z << 16);
  a[5] += cf * __uint_as_float(v.z & 0xffff0000u);
  a[6] += cf * __uint_as_float(v.w << 16);
  a[7] += cf * __uint_as_float(v.w & 0xffff0000u);
}

__device__ __forceinline__ uint4 self_pack(const float* a, uint4 sv, float d2,
                                           const float* bias, int fo) {
  float4 b0 = *(const float4*)(bias + fo);
  float4 b1 = *(const float4*)(bias + fo + 4);
  float o0 = a[0] + d2 * __uint_as_float(sv.x << 16) + b0.x;
  float o1 = a[1] + d2 * __uint_as_float(sv.x & 0xffff0000u) + b0.y;
  float o2 = a[2] + d2 * __uint_as_float(sv.y << 16) + b0.z;
  float o3 = a[3] + d2 * __uint_as_float(sv.y & 0xffff0000u) + b0.w;
  float o4 = a[4] + d2 * __uint_as_float(sv.z << 16) + b1.x;
  float o5 = a[5] + d2 * __uint_as_float(sv.z & 0xffff0000u) + b1.y;
  float o6 = a[6] + d2 * __uint_as_float(sv.w << 16) + b1.z;
  float o7 = a[7] + d2 * __uint_as_float(sv.w & 0xffff0000u) + b1.w;
  uint4 ou;
  ou.x = f2bf(o0) | ((u32)f2bf(o1) << 16);
  ou.y = f2bf(o2) | ((u32)f2bf(o3) << 16);
  ou.z = f2bf(o4) | ((u32)f2bf(o5) << 16);
  ou.w = f2bf(o6) | ((u32)f2bf(o7) << 16);
  return ou;
}

// GCN aggregate. blockIdx.y==0: chains 0&4 fused (shared set-0 edges, dual gather);
// blockIdx.y==y in 1..3: MST chain y. Wave per node; 4 edge-groups x 16 lanes x 8 bf16.
__global__ __launch_bounds__(256) void k_agg2(ZP p, const int* __restrict__ indptr,
                                              const int2* __restrict__ ent,
                                              const float* __restrict__ dinv, int4 entoff) {
  int y = blockIdx.y;
  int wv = threadIdx.x >> 6, lane = threadIdx.x & 63;
  int node = blockIdx.x * 4 + wv;
  if (node >= NN) return;
  int g = lane >> 4;
  int fo = (lane & 15) * 8;
  if (y == 0) {
    // dual: chains 0 and 4 on edge set 0 (entoff.x == 0)
    int beg = indptr[node], end = indptr[node + 1];
    const u16* __restrict__ Y0 = p.Y[0];
    const u16* __restrict__ Y4 = p.Y[4];
    float a0[8] = {0, 0, 0, 0, 0, 0, 0, 0};
    float a4[8] = {0, 0, 0, 0, 0, 0, 0, 0};
    for (int e = beg + g; e < end; e += 4) {
      int2 sc = ent[e];
      float cf = __int_as_float(sc.y);
      size_t ro = (size_t)sc.x * NH + fo;
      uint4 v0 = *(const uint4*)(Y0 + ro);
      uint4 v4 = *(const uint4*)(Y4 + ro);
      fma8(a0, v0, cf);
      fma8(a4, v4, cf);
    }
#pragma unroll
    for (int j = 0; j < 8; j++) {
      a0[j] += __shfl_xor(a0[j], 16);
      a0[j] += __shfl_xor(a0[j], 32);
      a4[j] += __shfl_xor(a4[j], 16);
      a4[j] += __shfl_xor(a4[j], 32);
    }
    if (g == 0) {
      float di = dinv[node];
      float d2 = di * di;
      size_t ro = (size_t)node * NH + fo;
      uint4 sv0 = *(const uint4*)(Y0 + ro);
      uint4 sv4 = *(const uint4*)(Y4 + ro);
      *(uint4*)(p.Xo[0] + ro) = self_pack(a0, sv0, d2, p.bias[0], fo);
      *(uint4*)(p.Xo[4] + ro) = self_pack(a4, sv4, d2, p.bias[4], fo);
    }
  } else {
    int s = y;  // set == chain for 1..3
    const int* ip = indptr + s * (NN + 1);
    int eb = (s == 1) ? entoff.y : ((s == 2) ? entoff.z : entoff.w);
    const u16* __restrict__ Y = p.Y[y];
    int beg = ip[node], end = ip[node + 1];
    const int2* __restrict__ ev = ent + eb;
    float a[8] = {0, 0, 0, 0, 0, 0, 0, 0};
    for (int e = beg + g; e < end; e += 4) {
      int2 sc = ev[e];
      float cf = __int_as_float(sc.y);
      uint4 v = *(const uint4*)(Y + (size_t)sc.x * NH + fo);
      fma8(a, v, cf);
    }
#pragma unroll
    for (int j = 0; j < 8; j++) {
      a[j] += __shfl_xor(a[j], 16);
      a[j] += __shfl_xor(a[j], 32);
    }
    if (g == 0) {
      float di = dinv[s * NN + node];
      float d2 = di * di;
      size_t ro = (size_t)node * NH + fo;
      uint4 sv = *(const uint4*)(Y + ro);
      *(uint4*)(p.Xo[y] + ro) = self_pack(a, sv, d2, p.bias[y], fo);
    }
  }
}

// graph-norm: one block per (graph, chain). Stats + normalize + leaky + M-row,
// zero atomics (graphs are contiguous row slabs since batch is sorted).
__global__ __launch_bounds__(256) void k_norm(ZP p, const int* __restrict__ gstart,
                                              const int* __restrict__ counts,
                                              float* __restrict__ Ml) {
  int g = blockIdx.x, zi = blockIdx.y;
  const u16* __restrict__ X = p.Xo[zi];
  u16* __restrict__ Xn = p.Xn[zi];
  int t = threadIdx.x;
  int j = t & 63;
  int f2 = j * 2;          // feature pair
  int rh = t >> 6;         // 4 row streams
  int start = gstart[g], cnt = counts[g];
  __shared__ float l_s0[256], l_s1[256], l_q0[256], l_q1[256];
  float s0 = 0.f, s1 = 0.f, q0 = 0.f, q1 = 0.f;
  for (int i = rh; i < cnt; i += 4) {
    u32 v = *(const u32*)(X + (size_t)(start + i) * NH + f2);
    float v0 = __uint_as_float(v << 16), v1 = __uint_as_float(v & 0xffff0000u);
    s0 += v0; q0 += v0 * v0;
    s1 += v1; q1 += v1 * v1;
  }
  l_s0[t] = s0; l_s1[t] = s1; l_q0[t] = q0; l_q1[t] = q1;
  __syncthreads();
  if (rh == 0) {
    l_s0[j] = l_s0[j] + l_s0[64 + j] + l_s0[128 + j] + l_s0[192 + j];
    l_s1[j] = l_s1[j] + l_s1[64 + j] + l_s1[128 + j] + l_s1[192 + j];
    l_q0[j] = l_q0[j] + l_q0[64 + j] + l_q0[128 + j] + l_q0[192 + j];
    l_q1[j] = l_q1[j] + l_q1[64 + j] + l_q1[128 + j] + l_q1[192 + j];
  }
  __syncthreads();
  float cntf = fmaxf((float)cnt, 1.f);
  float w0 = p.gw[zi][f2], w1 = p.gw[zi][f2 + 1];
  float b0 = p.gb[zi][f2], b1 = p.gb[zi][f2 + 1];
  float ms0 = p.gms[zi][f2], ms1 = p.gms[zi][f2 + 1];
  float mean0 = l_s0[j] / cntf, mean1 = l_s1[j] / cntf;
  float var0 = l_q0[j] / cntf - (2.f * ms0 - ms0 * ms0) * mean0 * mean0;
  float var1 = l_q1[j] / cntf - (2.f * ms1 - ms1 * ms1) * mean1 * mean1;
  float inv0 = rsqrtf(var0 + GEPS), inv1 = rsqrtf(var1 + GEPS);
  __syncthreads();  // all reads of l_* done before reuse as macc
  float m0 = 0.f, m1 = 0.f;
  for (int i = rh; i < cnt; i += 4) {
    size_t ro = (size_t)(start + i) * NH + f2;
    u32 v = *(const u32*)(X + ro);
    float v0 = __uint_as_float(v << 16), v1 = __uint_as_float(v & 0xffff0000u);
    float o0 = w0 * (v0 - ms0 * mean0) * inv0 + b0;
    float o1 = w1 * (v1 - ms1 * mean1) * inv1 + b1;
    o0 = (o0 >= 0.f) ? o0 : GSLOPE * o0;
    o1 = (o1 >= 0.f) ? o1 : GSLOPE * o1;
    *(u32*)(Xn + ro) = (u32)f2bf(o0) | ((u32)f2bf(o1) << 16);
    m0 += o0; m1 += o1;
  }
  l_s0[t] = m0; l_s1[t] = m1;
  __syncthreads();
  if (rh == 0) {
    float M0 = l_s0[j] + l_s0[64 + j] + l_s0[128 + j] + l_s0[192 + j];
    float M1 = l_s1[j] + l_s1[64 + j] + l_s1[128 + j] + l_s1[192 + j];
    int col = p.colbase[zi] + f2;
    Ml[(size_t)g * 640 + col] = M0;
    Ml[(size_t)g * 640 + col + 1] = M1;
  }
}

// out[g][f] = mean_l(M[l][g][:] @ mergeW[:,f]) / cnt + mergeb[f]
__global__ __launch_bounds__(256) void k_mergeout(const float* __restrict__ M,
                                                  const float* __restrict__ mergeW,
                                                  const float* __restrict__ mergeb,
                                                  const int* __restrict__ counts,
                                                  float* __restrict__ out) {
  int g = blockIdx.x;
  int f = threadIdx.x & 127, h = threadIdx.x >> 7;
  __shared__ float mrow[640];
  __shared__ float red[128];
  float acc = 0.f;
  for (int l = 0; l < NLAY; l++) {
    const float* Mr = M + ((size_t)l * NG + g) * 640;
    for (int i = threadIdx.x; i < 640; i += 256) mrow[i] = Mr[i];
    __syncthreads();
    float s = 0.f;
    int k0 = h * 320;
#pragma unroll 8
    for (int k = k0; k < k0 + 320; k++) s += mrow[k] * mergeW[(size_t)k * NH + f];
    if (h) red[f] = s;
    __syncthreads();
    if (!h) acc += s + red[f];
    __syncthreads();
  }
  if (!h) {
    float cnt = fmaxf((float)counts[g], 1.f);
    out[(size_t)g * NH + f] = acc / (3.f * cnt) + mergeb[f];
  }
}

// ---------------- host ----------------

struct Offs {
  size_t counts, gstart, deg, M, dinv, indptr, cursor, ent, wt, xbf, h0;
  size_t yb[NCH], xo[NCH], xn[NCH];
  size_t memset1_off, memset1_len, total;
};

static size_t build_offs(Offs& o, int Etot) {
  size_t off = 0;
  auto alloc = [&](size_t bytes) -> size_t {
    off = (off + 255) & ~(size_t)255;
    size_t s = off;
    off += bytes;
    return s;
  };
  o.counts = alloc(NG * 4);
  o.gstart = alloc(NG * 4);
  o.deg = alloc((size_t)4 * NN * 4);
  o.M = alloc((size_t)NLAY * NG * 640 * 4);
  o.memset1_off = o.deg;
  o.memset1_len = (o.M + (size_t)NLAY * NG * 640 * 4) - o.deg;
  o.dinv = alloc((size_t)4 * NN * 4);
  o.indptr = alloc((size_t)4 * (NN + 1) * 4);
  o.cursor = alloc((size_t)4 * (NN + 1) * 4);
  o.ent = alloc((size_t)Etot * 8);
  o.wt = alloc((size_t)7 * NH * NH * 2);
  o.xbf = alloc((size_t)NNP * NH * 2);
  o.h0 = alloc((size_t)NNP * NH * 2);
  for (int i = 0; i < NCH; i++) {
    o.yb[i] = alloc((size_t)NN * NH * 2);
    o.xo[i] = alloc((size_t)NN * NH * 2);
    o.xn[i] = alloc((size_t)NNP * NH * 2);
  }
  o.total = off;
  return off;
}

extern "C" void kernel_launch(void* const* d_in, const int* in_sizes, int n_in,
                              void* d_out, int out_size, void* d_ws, size_t ws_size,
                              hipStream_t stream) {
  if (n_in < 21) return;
  const float* x = (const float*)d_in[0];
  const float* embW = (const float*)d_in[1];
  const float* embb = (const float*)d_in[2];
  const float* mainW = (const float*)d_in[3];
  const float* mainb = (const float*)d_in[4];
  const float* maingw = (const float*)d_in[5];
  const float* maingb = (const float*)d_in[6];
  const float* maingms = (const float*)d_in[7];
  const float* locW = (const float*)d_in[8];
  const float* locb = (const float*)d_in[9];
  const float* locgw = (const float*)d_in[10];
  const float* locgb = (const float*)d_in[11];
  const float* locgms = (const float*)d_in[12];
  const float* mergeW = (const float*)d_in[13];
  const float* mergeb = (const float*)d_in[14];
  const int* edge_index = (const int*)d_in[15];
  // d_in[16] = edges0: permutation of edge_index under segment_sum -> reuse set 0
  const int* edges1 = (const int*)d_in[17];
  const int* edges2 = (const int*)d_in[18];
  const int* edges3 = (const int*)d_in[19];
  const int* batch = (const int*)d_in[20];

  int E0 = in_sizes[15] / 2;
  int E1 = in_sizes[17] / 2, E2 = in_sizes[18] / 2, E3 = in_sizes[19] / 2;
  int Etot = E0 + E1 + E2 + E3;
  int maxE = E0 > E1 ? E0 : E1;
  maxE = maxE > E2 ? maxE : E2;
  maxE = maxE > E3 ? maxE : E3;

  Offs o;
  if (build_offs(o, Etot) > ws_size) return;  // fail visibly

  char* ws = (char*)d_ws;
  int* counts = (int*)(ws + o.counts);
  int* gstart = (int*)(ws + o.gstart);
  int* deg = (int*)(ws + o.deg);
  float* M = (float*)(ws + o.M);
  float* dinv = (float*)(ws + o.dinv);
  int* indptr = (int*)(ws + o.indptr);
  int* cursor = (int*)(ws + o.cursor);
  int2* ent = (int2*)(ws + o.ent);
  u16* wt = (u16*)(ws + o.wt);
  u16* xbf = (u16*)(ws + o.xbf);
  u16* h0 = (u16*)(ws + o.h0);
  u16 *yb[NCH], *xo[NCH], *xn[NCH];
  for (int i = 0; i < NCH; i++) {
    yb[i] = (u16*)(ws + o.yb[i]);
    xo[i] = (u16*)(ws + o.xo[i]);
    xn[i] = (u16*)(ws + o.xn[i]);
  }

  ES4 es;
  es.e[0] = edge_index; es.e[1] = edges1; es.e[2] = edges2; es.e[3] = edges3;
  es.cnt[0] = E0; es.cnt[1] = E1; es.cnt[2] = E2; es.cnt[3] = E3;
  es.off[0] = 0; es.off[1] = E0; es.off[2] = E0 + E1; es.off[3] = E0 + E1 + E2;
  int4 entoff = make_int4(0, E0, E0 + E1, E0 + E1 + E2);

  hipMemsetAsync(ws + o.memset1_off, 0, o.memset1_len, stream);  // deg + M
  k_count2<<<1, 64, 0, stream>>>(batch, counts, gstart);
  k_deg<<<dim3((maxE + 255) / 256, 4), 256, 0, stream>>>(es, deg);
  k_scan<<<4, 1024, 0, stream>>>(deg, indptr, cursor, dinv);
  k_fill<<<dim3((maxE + 255) / 256, 4), 256, 0, stream>>>(es, dinv, cursor, ent);
  k_prepw<<<dim3(NH, 7), NH, 0, stream>>>(embW, locW, mainW, wt);
  k_cast<<<(NN * NH / 8 + 255) / 256, 256, 0, stream>>>(x, xbf);

  const int nrb = (NN + 63) / 64;  // 313

  // embedding: h0 = x @ embW + embb (bf16)
  {
    ZP pe = {};
    pe.A[0] = xbf; pe.W[0] = wt; pe.Y[0] = h0;
    k_gemm_bf<<<dim3(nrb, 1), 256, 0, stream>>>(pe, embb);
  }

  for (int l = 0; l < NLAY; l++) {
    ZP p = {};
    for (int zi = 0; zi < NCH; zi++) {
      bool isMain = (zi == 4);
      p.A[zi] = (l == 0) ? (const u16*)h0 : (const u16*)xn[zi];
      p.W[zi] = wt + (size_t)((isMain ? 4 : 1) + l) * NH * NH;
      p.Y[zi] = yb[zi];
      p.Xo[zi] = xo[zi];
      p.Xn[zi] = xn[zi];
      p.bias[zi] = (isMain ? mainb : locb) + (size_t)l * NH;
      p.gw[zi] = (isMain ? maingw : locgw) + (size_t)l * NH;
      p.gb[zi] = (isMain ? maingb : locgb) + (size_t)l * NH;
      p.gms[zi] = (isMain ? maingms : locgms) + (size_t)l * NH;
      p.set[zi] = (zi == 0 || zi == 4) ? 0 : zi;
      p.colbase[zi] = isMain ? 512 : zi * NH;
    }
    if (l == 0) {
      // chains 0..3 share A(h0) and W(locW[0]): compute once
      ZP pg = {};
      pg.A[0] = h0; pg.W[0] = wt + (size_t)1 * NH * NH; pg.Y[0] = yb[0];
      pg.A[1] = h0; pg.W[1] = wt + (size_t)4 * NH * NH; pg.Y[1] = yb[4];
      k_gemm_bf<<<dim3(nrb, 2), 256, 0, stream>>>(pg, (const float*)nullptr);
      p.Y[1] = yb[0]; p.Y[2] = yb[0]; p.Y[3] = yb[0];
    } else {
      k_gemm_bf<<<dim3(nrb, NCH), 256, 0, stream>>>(p, (const float*)nullptr);
    }
    k_agg2<<<dim3(NN / 4, 4), 256, 0, stream>>>(p, indptr, ent, dinv, entoff);
    k_norm<<<dim3(NG, NCH), 256, 0, stream>>>(p, gstart, counts, M + (size_t)l * NG * 640);
  }

  k_mergeout<<<NG, 256, 0, stream>>>(M, mergeW, mergeb, counts, (float*)d_out);
}

// Round 5
// 525.782 us; speedup vs baseline: 1.0658x; 1.0658x over previous
//
#include <hip/hip_runtime.h>

#define NN 20000      // nodes
#define NNP 20032     // padded rows (64-row GEMM tiles read past NN)
#define NH 128        // hidden
#define NG 64         // graphs
#define NLAY 3
#define NCH 5         // 4 splits + main
#define GEPS 1e-5f
#define GSLOPE 0.01f

typedef unsigned short u16;
typedef unsigned int u32;
typedef __attribute__((ext_vector_type(8))) short short8;
typedef __attribute__((ext_vector_type(4))) float float4v;

__device__ __forceinline__ u16 f2bf(float f) {
  union { float f; u32 u; } v; v.f = f;
  u32 r = (v.u + 0x7fffu + ((v.u >> 16) & 1u)) >> 16;
  return (u16)r;
}
__device__ __forceinline__ float bf2f(u16 u) { return __uint_as_float((u32)u << 16); }

struct ZP {
  const u16* A[NCH];     // GEMM input (bf16, NNP rows)
  const u16* W[NCH];     // GEMM weight, bf16 transposed [N][K]
  u16* Y[NCH];           // GEMM output / gather source (bf16)
  u16* Xo[NCH];          // post-agg pre-norm (bf16)
  u16* Xn[NCH];          // post-norm, next layer's A (bf16, NNP rows)
  const float* bias[NCH];
  const float* gw[NCH];
  const float* gb[NCH];
  const float* gms[NCH];
  int set[NCH];
  int colbase[NCH];
};

struct ES4 {
  const int* e[4];
  int cnt[4];
  int off[4];
};

// ---------------- setup kernels ----------------

// batch is sorted -> per-graph start/count via binary search, no atomics
__global__ void k_count2(const int* __restrict__ batch, int* __restrict__ counts,
                         int* __restrict__ gstart) {
  int g = threadIdx.x;
  if (g >= NG) return;
  auto lb = [&](int key) {
    int lo = 0, hi = NN;
    while (lo < hi) {
      int mid = (lo + hi) >> 1;
      if (batch[mid] < key) lo = mid + 1; else hi = mid;
    }
    return lo;
  };
  int a = lb(g), b = lb(g + 1);
  gstart[g] = a;
  counts[g] = b - a;
}

__global__ void k_deg(ES4 es, int* __restrict__ deg) {
  int s = blockIdx.y;
  int i = blockIdx.x * 256 + threadIdx.x;
  int E = es.cnt[s];
  if (i < E) atomicAdd(&deg[s * NN + es.e[s][E + i]], 1);
}

// exclusive scan of deg -> indptr (+cursor copy) and dinv = rsqrt(deg+1) fused
__global__ void k_scan(const int* __restrict__ deg, int* __restrict__ indptr,
                       int* __restrict__ cursor, float* __restrict__ dinv) {
  int s = blockIdx.x;
  const int* d = deg + s * NN;
  int* ip = indptr + s * (NN + 1);
  int* cu = cursor + s * (NN + 1);
  __shared__ int part[1024];
  int t = threadIdx.x;
  const int CH = (NN + 1023) / 1024;
  int base = t * CH;
  int sum = 0;
  for (int j = 0; j < CH; j++) {
    int idx = base + j;
    if (idx < NN) {
      int dv = d[idx];
      sum += dv;
      dinv[s * NN + idx] = rsqrtf((float)dv + 1.0f);
    }
  }
  part[t] = sum;
  __syncthreads();
  for (int off = 1; off < 1024; off <<= 1) {
    int v = part[t];
    int u = (t >= off) ? part[t - off] : 0;
    __syncthreads();
    part[t] = v + u;
    __syncthreads();
  }
  int run = (t == 0) ? 0 : part[t - 1];
  for (int j = 0; j < CH; j++) {
    int idx = base + j;
    if (idx < NN) { ip[idx] = run; cu[idx] = run; run += d[idx]; }
  }
  if (t == 1023) { ip[NN] = run; cu[NN] = run; }
}

__global__ void k_fill(ES4 es, const float* __restrict__ dinv, int* __restrict__ cursor,
                       int2* __restrict__ ent) {
  int s = blockIdx.y;
  int i = blockIdx.x * 256 + threadIdx.x;
  int E = es.cnt[s];
  if (i >= E) return;
  int src = es.e[s][i];
  int dst = es.e[s][E + i];
  int pos = atomicAdd(&cursor[s * (NN + 1) + dst], 1);
  float c = dinv[s * NN + src] * dinv[s * NN + dst];
  ent[es.off[s] + pos] = make_int2(src, __float_as_int(c));
}

// weights: fp32 [K][N] -> bf16 transposed [N][K]; mats: 0=emb, 1-3=loc, 4-6=main
__global__ void k_prepw(const float* __restrict__ embW, const float* __restrict__ locW,
                        const float* __restrict__ mainW, u16* __restrict__ wt) {
  int mat = blockIdx.y;
  int n = blockIdx.x;
  int k = threadIdx.x;
  const float* W = (mat == 0) ? embW : ((mat <= 3) ? locW + (mat - 1) * NH * NH
                                                   : mainW + (mat - 4) * NH * NH);
  wt[(size_t)mat * NH * NH + n * NH + k] = f2bf(W[(size_t)k * NH + n]);
}

__global__ void k_cast(const float* __restrict__ x, u16* __restrict__ xb) {
  int i = (blockIdx.x * 256 + threadIdx.x) * 8;
  if (i >= NN * NH) return;
  float4 a = *(const float4*)(x + i);
  float4 b = *(const float4*)(x + i + 4);
  uint4 o;
  o.x = f2bf(a.x) | ((u32)f2bf(a.y) << 16);
  o.y = f2bf(a.z) | ((u32)f2bf(a.w) << 16);
  o.z = f2bf(b.x) | ((u32)f2bf(b.y) << 16);
  o.w = f2bf(b.z) | ((u32)f2bf(b.w) << 16);
  *(uint4*)(xb + i) = o;
}

// ---------------- compute kernels ----------------

// Y[z] = A[z] @ Wt[z]^T (+gbias). bf16 MFMA 16x16x32, 64-row tile, K=128 in LDS.
__global__ __launch_bounds__(256) void k_gemm_bf(ZP p, const float* __restrict__ gbias) {
  int zi = blockIdx.y;
  const u16* __restrict__ A = p.A[zi];
  const u16* __restrict__ Wt = p.W[zi];
  u16* __restrict__ Y = p.Y[zi];
  __shared__ u16 As[64][136];   // +8 pad: 2-way bank aliasing only
  __shared__ u16 Bs[128][136];
  int t = threadIdx.x;
  int row0 = blockIdx.x * 64;
  int c = t & 15, rs = t >> 4;
#pragma unroll
  for (int pass = 0; pass < 4; pass++) {
    int r = pass * 16 + rs;
    *(uint4*)(&As[r][c * 8]) = *(const uint4*)(A + (size_t)(row0 + r) * NH + c * 8);
  }
#pragma unroll
  for (int pass = 0; pass < 8; pass++) {
    int n = pass * 16 + rs;
    *(uint4*)(&Bs[n][c * 8]) = *(const uint4*)(Wt + (size_t)n * NH + c * 8);
  }
  __syncthreads();
  int lane = t & 63, w = t >> 6;
  int m16 = lane & 15, quad = lane >> 4;
  float4v acc[8];
#pragma unroll
  for (int i = 0; i < 8; i++) acc[i] = (float4v)(0.f);
#pragma unroll
  for (int kk = 0; kk < 4; kk++) {
    short8 av = *(const short8*)(&As[w * 16 + m16][kk * 32 + quad * 8]);
#pragma unroll
    for (int ct = 0; ct < 8; ct++) {
      short8 bv = *(const short8*)(&Bs[ct * 16 + m16][kk * 32 + quad * 8]);
      acc[ct] = __builtin_amdgcn_mfma_f32_16x16x32_bf16(av, bv, acc[ct], 0, 0, 0);
    }
  }
  __syncthreads();
  // epilogue: C/D layout col=lane&15, row=quad*4+reg -> LDS bounce -> 16B stores
#pragma unroll
  for (int ct = 0; ct < 8; ct++) {
    float bv = gbias ? gbias[ct * 16 + m16] : 0.f;
#pragma unroll
    for (int r = 0; r < 4; r++) {
      As[w * 16 + quad * 4 + r][ct * 16 + m16] = f2bf(acc[ct][r] + bv);
    }
  }
  __syncthreads();
#pragma unroll
  for (int pass = 0; pass < 4; pass++) {
    int r = pass * 16 + rs;
    int gr = row0 + r;
    if (gr < NN) *(uint4*)(Y + (size_t)gr * NH + c * 8) = *(const uint4*)(&As[r][c * 8]);
  }
}

__device__ __forceinline__ void fma8(float* a, uint4 v, float cf) {
  a[0] += cf * __uint_as_float(v.x << 16);
  a[1] += cf * __uint_as_float(v.x & 0xffff0000u);
  a[2] += cf * __uint_as_float(v.y << 16);
  a[3] += cf * __uint_as_float(v.y & 0xffff0000u);
  a[4] += cf * __uint_as_float(v.z << 16);
  a[5] += cf * __uint_as_float(v.z & 0xffff0000u);
  a[6] += cf * __uint_as_float(v.w << 16);
  a[7] += cf * __uint_as_float(v.w & 0xffff0000u);
}

__device__ __forceinline__ uint4 self_pack(const float* a, uint4 sv, float d2,
                                           const float* bias, int fo) {
  float4 b0 = *(const float4*)(bias + fo);
  float4 b1 = *(const float4*)(bias + fo + 4);
  float o0 = a[0] + d2 * __uint_as_float(sv.x << 16) + b0.x;
  float o1 = a[1] + d2 * __uint_as_float(sv.x & 0xffff0000u) + b0.y;
  float o2 = a[2] + d2 * __uint_as_float(sv.y << 16) + b0.z;
  float o3 = a[3] + d2 * __uint_as_float(sv.y & 0xffff0000u) + b0.w;
  float o4 = a[4] + d2 * __uint_as_float(sv.z << 16) + b1.x;
  float o5 = a[5] + d2 * __uint_as_float(sv.z & 0xffff0000u) + b1.y;
  float o6 = a[6] + d2 * __uint_as_float(sv.w << 16) + b1.z;
  float o7 = a[7] + d2 * __uint_as_float(sv.w & 0xffff0000u) + b1.w;
  uint4 ou;
  ou.x = f2bf(o0) | ((u32)f2bf(o1) << 16);
  ou.y = f2bf(o2) | ((u32)f2bf(o3) << 16);
  ou.z = f2bf(o4) | ((u32)f2bf(o5) << 16);
  ou.w = f2bf(o6) | ((u32)f2bf(o7) << 16);
  return ou;
}

// GCN aggregate. blockIdx.y==0: chains 0&4 fused (shared set-0 edges, dual gather);
// blockIdx.y==y in 1..3: MST chain y. Wave per node; 4 edge-groups x 16 lanes x 8 bf16.
__global__ __launch_bounds__(256) void k_agg2(ZP p, const int* __restrict__ indptr,
                                              const int2* __restrict__ ent,
                                              const float* __restrict__ dinv, int4 entoff) {
  int y = blockIdx.y;
  int wv = threadIdx.x >> 6, lane = threadIdx.x & 63;
  int node = blockIdx.x * 4 + wv;
  if (node >= NN) return;
  int g = lane >> 4;
  int fo = (lane & 15) * 8;
  if (y == 0) {
    // dual: chains 0 and 4 on edge set 0 (entoff.x == 0)
    int beg = indptr[node], end = indptr[node + 1];
    const u16* __restrict__ Y0 = p.Y[0];
    const u16* __restrict__ Y4 = p.Y[4];
    float a0[8] = {0, 0, 0, 0, 0, 0, 0, 0};
    float a4[8] = {0, 0, 0, 0, 0, 0, 0, 0};
    for (int e = beg + g; e < end; e += 4) {
      int2 sc = ent[e];
      float cf = __int_as_float(sc.y);
      size_t ro = (size_t)sc.x * NH + fo;
      uint4 v0 = *(const uint4*)(Y0 + ro);
      uint4 v4 = *(const uint4*)(Y4 + ro);
      fma8(a0, v0, cf);
      fma8(a4, v4, cf);
    }
#pragma unroll
    for (int j = 0; j < 8; j++) {
      a0[j] += __shfl_xor(a0[j], 16);
      a0[j] += __shfl_xor(a0[j], 32);
      a4[j] += __shfl_xor(a4[j], 16);
      a4[j] += __shfl_xor(a4[j], 32);
    }
    if (g == 0) {
      float di = dinv[node];
      float d2 = di * di;
      size_t ro = (size_t)node * NH + fo;
      uint4 sv0 = *(const uint4*)(Y0 + ro);
      uint4 sv4 = *(const uint4*)(Y4 + ro);
      *(uint4*)(p.Xo[0] + ro) = self_pack(a0, sv0, d2, p.bias[0], fo);
      *(uint4*)(p.Xo[4] + ro) = self_pack(a4, sv4, d2, p.bias[4], fo);
    }
  } else {
    int s = y;  // set == chain for 1..3
    const int* ip = indptr + s * (NN + 1);
    int eb = (s == 1) ? entoff.y : ((s == 2) ? entoff.z : entoff.w);
    const u16* __restrict__ Y = p.Y[y];
    int beg = ip[node], end = ip[node + 1];
    const int2* __restrict__ ev = ent + eb;
    float a[8] = {0, 0, 0, 0, 0, 0, 0, 0};
    for (int e = beg + g; e < end; e += 4) {
      int2 sc = ev[e];
      float cf = __int_as_float(sc.y);
      uint4 v = *(const uint4*)(Y + (size_t)sc.x * NH + fo);
      fma8(a, v, cf);
    }
#pragma unroll
    for (int j = 0; j < 8; j++) {
      a[j] += __shfl_xor(a[j], 16);
      a[j] += __shfl_xor(a[j], 32);
    }
    if (g == 0) {
      float di = dinv[s * NN + node];
      float d2 = di * di;
      size_t ro = (size_t)node * NH + fo;
      uint4 sv = *(const uint4*)(Y + ro);
      *(uint4*)(p.Xo[y] + ro) = self_pack(a, sv, d2, p.bias[y], fo);
    }
  }
}

// stats: grid (313, NCH), 256 thr = 64 feature-pairs x 4 row-streams, u32 loads,
// flush-on-graph-change atomics (batch sorted -> <=2 graphs per 64-row window)
__global__ __launch_bounds__(256) void k_stats(ZP p, const int* __restrict__ batch,
                                               float* __restrict__ ssum, float* __restrict__ ssq) {
  int zi = blockIdx.y;
  const u16* __restrict__ X = p.Xo[zi];
  int t = threadIdx.x;
  int f2 = (t & 63) * 2, rh = t >> 6;
  int r0 = blockIdx.x * 64;
  float s0 = 0.f, s1 = 0.f, q0 = 0.f, q1 = 0.f;
  int curg = -1;
  for (int i = rh; i < 64; i += 4) {
    int r = r0 + i;
    if (r >= NN) break;
    int g = batch[r];
    if (g != curg) {
      if (curg >= 0) {
        float* su = &ssum[(size_t)(zi * NG + curg) * NH + f2];
        float* sq = &ssq[(size_t)(zi * NG + curg) * NH + f2];
        atomicAdd(su, s0); atomicAdd(su + 1, s1);
        atomicAdd(sq, q0); atomicAdd(sq + 1, q1);
      }
      curg = g; s0 = s1 = q0 = q1 = 0.f;
    }
    u32 v = *(const u32*)(X + (size_t)r * NH + f2);
    float v0 = __uint_as_float(v << 16), v1 = __uint_as_float(v & 0xffff0000u);
    s0 += v0; q0 += v0 * v0;
    s1 += v1; q1 += v1 * v1;
  }
  if (curg >= 0) {
    float* su = &ssum[(size_t)(zi * NG + curg) * NH + f2];
    float* sq = &ssq[(size_t)(zi * NG + curg) * NH + f2];
    atomicAdd(su, s0); atomicAdd(su + 1, s1);
    atomicAdd(sq, q0); atomicAdd(sq + 1, q1);
  }
}

// graph-norm + leaky -> bf16 Xn, accumulate per-graph sums into M[l] (atomics)
__global__ __launch_bounds__(256) void k_apply(ZP p, const int* __restrict__ batch,
                                               const int* __restrict__ counts,
                                               const float* __restrict__ ssum,
                                               const float* __restrict__ ssq,
                                               float* __restrict__ Ml) {
  int zi = blockIdx.y;
  const u16* __restrict__ X = p.Xo[zi];
  u16* __restrict__ Xn = p.Xn[zi];
  int t = threadIdx.x;
  int f2 = (t & 63) * 2, rh = t >> 6;
  int r0 = blockIdx.x * 64;
  float w0 = p.gw[zi][f2], w1 = p.gw[zi][f2 + 1];
  float b0 = p.gb[zi][f2], b1 = p.gb[zi][f2 + 1];
  float ms0 = p.gms[zi][f2], ms1 = p.gms[zi][f2 + 1];
  int col = p.colbase[zi] + f2;
  float m0 = 0.f, m1 = 0.f;
  int curg = -1;
  float mean0 = 0.f, mean1 = 0.f, inv0 = 0.f, inv1 = 0.f;
  for (int i = rh; i < 64; i += 4) {
    int r = r0 + i;
    if (r >= NN) break;
    int g = batch[r];
    if (g != curg) {
      if (curg >= 0) {
        atomicAdd(&Ml[(size_t)curg * 640 + col], m0);
        atomicAdd(&Ml[(size_t)curg * 640 + col + 1], m1);
      }
      m0 = m1 = 0.f;
      curg = g;
      float cnt = fmaxf((float)counts[g], 1.f);
      size_t sb = (size_t)(zi * NG + g) * NH + f2;
      mean0 = ssum[sb] / cnt;
      mean1 = ssum[sb + 1] / cnt;
      float var0 = ssq[sb] / cnt - (2.f * ms0 - ms0 * ms0) * mean0 * mean0;
      float var1 = ssq[sb + 1] / cnt - (2.f * ms1 - ms1 * ms1) * mean1 * mean1;
      inv0 = rsqrtf(var0 + GEPS);
      inv1 = rsqrtf(var1 + GEPS);
    }
    size_t ro = (size_t)r * NH + f2;
    u32 v = *(const u32*)(X + ro);
    float v0 = __uint_as_float(v << 16), v1 = __uint_as_float(v & 0xffff0000u);
    float o0 = w0 * (v0 - ms0 * mean0) * inv0 + b0;
    float o1 = w1 * (v1 - ms1 * mean1) * inv1 + b1;
    o0 = (o0 >= 0.f) ? o0 : GSLOPE * o0;
    o1 = (o1 >= 0.f) ? o1 : GSLOPE * o1;
    *(u32*)(Xn + ro) = (u32)f2bf(o0) | ((u32)f2bf(o1) << 16);
    m0 += o0; m1 += o1;
  }
  if (curg >= 0) {
    atomicAdd(&Ml[(size_t)curg * 640 + col], m0);
    atomicAdd(&Ml[(size_t)curg * 640 + col + 1], m1);
  }
}

// out[g][f] = mean_l(M[l][g][:] @ mergeW[:,f]) / cnt + mergeb[f]
__global__ __launch_bounds__(256) void k_mergeout(const float* __restrict__ M,
                                                  const float* __restrict__ mergeW,
                                                  const float* __restrict__ mergeb,
                                                  const int* __restrict__ counts,
                                                  float* __restrict__ out) {
  int g = blockIdx.x;
  int f = threadIdx.x & 127, h = threadIdx.x >> 7;
  __shared__ float mrow[640];
  __shared__ float red[128];
  float acc = 0.f;
  for (int l = 0; l < NLAY; l++) {
    const float* Mr = M + ((size_t)l * NG + g) * 640;
    for (int i = threadIdx.x; i < 640; i += 256) mrow[i] = Mr[i];
    __syncthreads();
    float s = 0.f;
    int k0 = h * 320;
#pragma unroll 8
    for (int k = k0; k < k0 + 320; k++) s += mrow[k] * mergeW[(size_t)k * NH + f];
    if (h) red[f] = s;
    __syncthreads();
    if (!h) acc += s + red[f];
    __syncthreads();
  }
  if (!h) {
    float cnt = fmaxf((float)counts[g], 1.f);
    out[(size_t)g * NH + f] = acc / (3.f * cnt) + mergeb[f];
  }
}

// ---------------- host ----------------

struct Offs {
  size_t counts, gstart, deg, M, stats, dinv, indptr, cursor, ent, wt, xbf, h0;
  size_t yb[NCH], xo[NCH], xn[NCH];
  size_t memset1_off, memset1_len, total;
};

static size_t build_offs(Offs& o, int Etot) {
  size_t off = 0;
  auto alloc = [&](size_t bytes) -> size_t {
    off = (off + 255) & ~(size_t)255;
    size_t s = off;
    off += bytes;
    return s;
  };
  o.counts = alloc(NG * 4);
  o.gstart = alloc(NG * 4);
  o.deg = alloc((size_t)4 * NN * 4);
  o.M = alloc((size_t)NLAY * NG * 640 * 4);
  // per-layer stats (ssum+ssq), all zeroed once in the startup memset
  o.stats = alloc((size_t)NLAY * 2 * NCH * NG * NH * 4);
  o.memset1_off = o.deg;
  o.memset1_len = (o.stats + (size_t)NLAY * 2 * NCH * NG * NH * 4) - o.deg;
  o.dinv = alloc((size_t)4 * NN * 4);
  o.indptr = alloc((size_t)4 * (NN + 1) * 4);
  o.cursor = alloc((size_t)4 * (NN + 1) * 4);
  o.ent = alloc((size_t)Etot * 8);
  o.wt = alloc((size_t)7 * NH * NH * 2);
  o.xbf = alloc((size_t)NNP * NH * 2);
  o.h0 = alloc((size_t)NNP * NH * 2);
  for (int i = 0; i < NCH; i++) {
    o.yb[i] = alloc((size_t)NN * NH * 2);
    o.xo[i] = alloc((size_t)NN * NH * 2);
    o.xn[i] = alloc((size_t)NNP * NH * 2);
  }
  o.total = off;
  return off;
}

extern "C" void kernel_launch(void* const* d_in, const int* in_sizes, int n_in,
                              void* d_out, int out_size, void* d_ws, size_t ws_size,
                              hipStream_t stream) {
  if (n_in < 21) return;
  const float* x = (const float*)d_in[0];
  const float* embW = (const float*)d_in[1];
  const float* embb = (const float*)d_in[2];
  const float* mainW = (const float*)d_in[3];
  const float* mainb = (const float*)d_in[4];
  const float* maingw = (const float*)d_in[5];
  const float* maingb = (const float*)d_in[6];
  const float* maingms = (const float*)d_in[7];
  const float* locW = (const float*)d_in[8];
  const float* locb = (const float*)d_in[9];
  const float* locgw = (const float*)d_in[10];
  const float* locgb = (const float*)d_in[11];
  const float* locgms = (const float*)d_in[12];
  const float* mergeW = (const float*)d_in[13];
  const float* mergeb = (const float*)d_in[14];
  const int* edge_index = (const int*)d_in[15];
  // d_in[16] = edges0: permutation of edge_index under segment_sum -> reuse set 0
  const int* edges1 = (const int*)d_in[17];
  const int* edges2 = (const int*)d_in[18];
  const int* edges3 = (const int*)d_in[19];
  const int* batch = (const int*)d_in[20];

  int E0 = in_sizes[15] / 2;
  int E1 = in_sizes[17] / 2, E2 = in_sizes[18] / 2, E3 = in_sizes[19] / 2;
  int Etot = E0 + E1 + E2 + E3;
  int maxE = E0 > E1 ? E0 : E1;
  maxE = maxE > E2 ? maxE : E2;
  maxE = maxE > E3 ? maxE : E3;

  Offs o;
  if (build_offs(o, Etot) > ws_size) return;  // fail visibly

  char* ws = (char*)d_ws;
  int* counts = (int*)(ws + o.counts);
  int* gstart = (int*)(ws + o.gstart);
  int* deg = (int*)(ws + o.deg);
  float* M = (float*)(ws + o.M);
  float* stats = (float*)(ws + o.stats);
  float* dinv = (float*)(ws + o.dinv);
  int* indptr = (int*)(ws + o.indptr);
  int* cursor = (int*)(ws + o.cursor);
  int2* ent = (int2*)(ws + o.ent);
  u16* wt = (u16*)(ws + o.wt);
  u16* xbf = (u16*)(ws + o.xbf);
  u16* h0 = (u16*)(ws + o.h0);
  u16 *yb[NCH], *xo[NCH], *xn[NCH];
  for (int i = 0; i < NCH; i++) {
    yb[i] = (u16*)(ws + o.yb[i]);
    xo[i] = (u16*)(ws + o.xo[i]);
    xn[i] = (u16*)(ws + o.xn[i]);
  }

  ES4 es;
  es.e[0] = edge_index; es.e[1] = edges1; es.e[2] = edges2; es.e[3] = edges3;
  es.cnt[0] = E0; es.cnt[1] = E1; es.cnt[2] = E2; es.cnt[3] = E3;
  es.off[0] = 0; es.off[1] = E0; es.off[2] = E0 + E1; es.off[3] = E0 + E1 + E2;
  int4 entoff = make_int4(0, E0, E0 + E1, E0 + E1 + E2);

  hipMemsetAsync(ws + o.memset1_off, 0, o.memset1_len, stream);  // deg + M + stats
  k_count2<<<1, 64, 0, stream>>>(batch, counts, gstart);
  k_deg<<<dim3((maxE + 255) / 256, 4), 256, 0, stream>>>(es, deg);
  k_scan<<<4, 1024, 0, stream>>>(deg, indptr, cursor, dinv);
  k_fill<<<dim3((maxE + 255) / 256, 4), 256, 0, stream>>>(es, dinv, cursor, ent);
  k_prepw<<<dim3(NH, 7), NH, 0, stream>>>(embW, locW, mainW, wt);
  k_cast<<<(NN * NH / 8 + 255) / 256, 256, 0, stream>>>(x, xbf);

  const int nrb = (NN + 63) / 64;  // 313

  // embedding: h0 = x @ embW + embb (bf16)
  {
    ZP pe = {};
    pe.A[0] = xbf; pe.W[0] = wt; pe.Y[0] = h0;
    k_gemm_bf<<<dim3(nrb, 1), 256, 0, stream>>>(pe, embb);
  }

  const size_t statstride = (size_t)2 * NCH * NG * NH;
  for (int l = 0; l < NLAY; l++) {
    float* ssum = stats + (size_t)l * statstride;
    float* ssq = ssum + (size_t)NCH * NG * NH;
    ZP p = {};
    for (int zi = 0; zi < NCH; zi++) {
      bool isMain = (zi == 4);
      p.A[zi] = (l == 0) ? (const u16*)h0 : (const u16*)xn[zi];
      p.W[zi] = wt + (size_t)((isMain ? 4 : 1) + l) * NH * NH;
      p.Y[zi] = yb[zi];
      p.Xo[zi] = xo[zi];
      p.Xn[zi] = xn[zi];
      p.bias[zi] = (isMain ? mainb : locb) + (size_t)l * NH;
      p.gw[zi] = (isMain ? maingw : locgw) + (size_t)l * NH;
      p.gb[zi] = (isMain ? maingb : locgb) + (size_t)l * NH;
      p.gms[zi] = (isMain ? maingms : locgms) + (size_t)l * NH;
      p.set[zi] = (zi == 0 || zi == 4) ? 0 : zi;
      p.colbase[zi] = isMain ? 512 : zi * NH;
    }
    if (l == 0) {
      // chains 0..3 share A(h0) and W(locW[0]): compute once
      ZP pg = {};
      pg.A[0] = h0; pg.W[0] = wt + (size_t)1 * NH * NH; pg.Y[0] = yb[0];
      pg.A[1] = h0; pg.W[1] = wt + (size_t)4 * NH * NH; pg.Y[1] = yb[4];
      k_gemm_bf<<<dim3(nrb, 2), 256, 0, stream>>>(pg, (const float*)nullptr);
      p.Y[1] = yb[0]; p.Y[2] = yb[0]; p.Y[3] = yb[0];
    } else {
      k_gemm_bf<<<dim3(nrb, NCH), 256, 0, stream>>>(p, (const float*)nullptr);
    }
    k_agg2<<<dim3(NN / 4, 4), 256, 0, stream>>>(p, indptr, ent, dinv, entoff);
    k_stats<<<dim3(nrb, NCH), 256, 0, stream>>>(p, batch, ssum, ssq);
    k_apply<<<dim3(nrb, NCH), 256, 0, stream>>>(p, batch, counts, ssum, ssq,
                                                M + (size_t)l * NG * 640);
  }

  k_mergeout<<<NG, 256, 0, stream>>>(M, mergeW, mergeb, counts, (float*)d_out);
}

// Round 6
// 493.048 us; speedup vs baseline: 1.1365x; 1.0664x over previous
//
#include <hip/hip_runtime.h>

#define NN 20000      // nodes
#define NNP 20032     // padded rows (64-row GEMM tiles read past NN)
#define NH 128        // hidden
#define NG 64         // graphs
#define NLAY 3
#define NCH 5         // 4 splits + main
#define GEPS 1e-5f
#define GSLOPE 0.01f

typedef unsigned short u16;
typedef unsigned int u32;
typedef __attribute__((ext_vector_type(8))) short short8;
typedef __attribute__((ext_vector_type(4))) float float4v;

__device__ __forceinline__ u16 f2bf(float f) {
  union { float f; u32 u; } v; v.f = f;
  u32 r = (v.u + 0x7fffu + ((v.u >> 16) & 1u)) >> 16;
  return (u16)r;
}
__device__ __forceinline__ float bf2f(u16 u) { return __uint_as_float((u32)u << 16); }

struct ZP {
  const u16* A[NCH];     // GEMM input (bf16, NNP rows)
  const u16* W[NCH];     // GEMM weight, bf16 transposed [N][K]
  u16* Y[NCH];           // GEMM output / gather source (bf16)
  u16* Xo[NCH];          // post-agg pre-norm (bf16)
  u16* Xn[NCH];          // post-norm, next layer's A (bf16, NNP rows)
  const float* bias[NCH];
  const float* gw[NCH];
  const float* gb[NCH];
  const float* gms[NCH];
  int set[NCH];
  int colbase[NCH];
};

struct ES4 {
  const int* e[4];
  int cnt[4];
  int off[4];
};

// ---------------- setup kernels ----------------

// batch is sorted -> per-graph start/count via binary search, no atomics
__global__ void k_count2(const int* __restrict__ batch, int* __restrict__ counts,
                         int* __restrict__ gstart) {
  int g = threadIdx.x;
  if (g >= NG) return;
  auto lb = [&](int key) {
    int lo = 0, hi = NN;
    while (lo < hi) {
      int mid = (lo + hi) >> 1;
      if (batch[mid] < key) lo = mid + 1; else hi = mid;
    }
    return lo;
  };
  int a = lb(g), b = lb(g + 1);
  gstart[g] = a;
  counts[g] = b - a;
}

__global__ void k_deg(ES4 es, int* __restrict__ deg) {
  int s = blockIdx.y;
  int i = blockIdx.x * 256 + threadIdx.x;
  int E = es.cnt[s];
  if (i < E) atomicAdd(&deg[s * NN + es.e[s][E + i]], 1);
}

// coalesced tile-wise exclusive scan of deg -> indptr (+cursor) and dinv, fused.
// 1024-element tiles: lane t owns element tile*1024+t (coalesced loads/stores),
// wave-shuffle inclusive scan + 16 wave-sums scanned by wave 0. 3 barriers/tile.
__global__ __launch_bounds__(1024) void k_scan(const int* __restrict__ deg,
                                               int* __restrict__ indptr,
                                               int* __restrict__ cursor,
                                               float* __restrict__ dinv) {
  int s = blockIdx.x;
  const int* d = deg + s * NN;
  int* ip = indptr + s * (NN + 1);
  int* cu = cursor + s * (NN + 1);
  int t = threadIdx.x;
  int lane = t & 63, wv = t >> 6;  // 16 waves
  __shared__ int wsum[16];
  int run = 0;
  const int NT = (NN + 1023) / 1024;  // 20
  for (int tile = 0; tile < NT; tile++) {
    int idx = tile * 1024 + t;
    int v = 0;
    if (idx < NN) {
      v = d[idx];
      dinv[s * NN + idx] = rsqrtf((float)v + 1.0f);
    }
    int x = v;
#pragma unroll
    for (int o = 1; o < 64; o <<= 1) {
      int y = __shfl_up(x, o);
      if (lane >= o) x += y;
    }
    if (lane == 63) wsum[wv] = x;
    __syncthreads();
    if (wv == 0) {
      int y = (lane < 16) ? wsum[lane] : 0;
#pragma unroll
      for (int o = 1; o < 16; o <<= 1) {
        int z = __shfl_up(y, o);
        if (lane >= o) y += z;
      }
      if (lane < 16) wsum[lane] = y;
    }
    __syncthreads();
    int waveoff = (wv == 0) ? 0 : wsum[wv - 1];
    int excl = run + waveoff + x - v;  // exclusive prefix
    if (idx < NN) { ip[idx] = excl; cu[idx] = excl; }
    run += wsum[15];
    __syncthreads();  // protect wsum before next tile overwrites
  }
  if (t == 0) { ip[NN] = run; cu[NN] = run; }
}

__global__ void k_fill(ES4 es, const float* __restrict__ dinv, int* __restrict__ cursor,
                       int2* __restrict__ ent) {
  int s = blockIdx.y;
  int i = blockIdx.x * 256 + threadIdx.x;
  int E = es.cnt[s];
  if (i >= E) return;
  int src = es.e[s][i];
  int dst = es.e[s][E + i];
  int pos = atomicAdd(&cursor[s * (NN + 1) + dst], 1);
  float c = dinv[s * NN + src] * dinv[s * NN + dst];
  ent[es.off[s] + pos] = make_int2(src, __float_as_int(c));
}

// weights: fp32 [K][N] -> bf16 transposed [N][K] via LDS 32x32 tile (both sides
// coalesced). mats: 0=emb, 1-3=loc, 4-6=main. grid (16, 7), block 256.
__global__ __launch_bounds__(256) void k_prepw(const float* __restrict__ embW,
                                               const float* __restrict__ locW,
                                               const float* __restrict__ mainW,
                                               u16* __restrict__ wt) {
  int mat = blockIdx.y;
  const float* W = (mat == 0) ? embW : ((mat <= 3) ? locW + (mat - 1) * NH * NH
                                                   : mainW + (mat - 4) * NH * NH);
  int tile = blockIdx.x;
  int tk = (tile >> 2) * 32;   // K-tile origin (row of W)
  int tn = (tile & 3) * 32;    // N-tile origin (col of W)
  __shared__ float tl[32][33];
  int c = threadIdx.x & 31, r = threadIdx.x >> 5;  // 32 x 8
#pragma unroll
  for (int rr = 0; rr < 32; rr += 8)
    tl[r + rr][c] = W[(size_t)(tk + r + rr) * NH + tn + c];
  __syncthreads();
#pragma unroll
  for (int rr = 0; rr < 32; rr += 8)
    wt[(size_t)mat * NH * NH + (size_t)(tn + r + rr) * NH + tk + c] = f2bf(tl[c][r + rr]);
}

__global__ void k_cast(const float* __restrict__ x, u16* __restrict__ xb) {
  int i = (blockIdx.x * 256 + threadIdx.x) * 8;
  if (i >= NN * NH) return;
  float4 a = *(const float4*)(x + i);
  float4 b = *(const float4*)(x + i + 4);
  uint4 o;
  o.x = f2bf(a.x) | ((u32)f2bf(a.y) << 16);
  o.y = f2bf(a.z) | ((u32)f2bf(a.w) << 16);
  o.z = f2bf(b.x) | ((u32)f2bf(b.y) << 16);
  o.w = f2bf(b.z) | ((u32)f2bf(b.w) << 16);
  *(uint4*)(xb + i) = o;
}

// ---------------- compute kernels ----------------

// Y[z] = A[z] @ Wt[z]^T (+gbias). bf16 MFMA 16x16x32, 64-row tile, K=128 in LDS.
__global__ __launch_bounds__(256) void k_gemm_bf(ZP p, const float* __restrict__ gbias) {
  int zi = blockIdx.y;
  const u16* __restrict__ A = p.A[zi];
  const u16* __restrict__ Wt = p.W[zi];
  u16* __restrict__ Y = p.Y[zi];
  __shared__ u16 As[64][136];   // +8 pad: 2-way bank aliasing only
  __shared__ u16 Bs[128][136];
  int t = threadIdx.x;
  int row0 = blockIdx.x * 64;
  int c = t & 15, rs = t >> 4;
#pragma unroll
  for (int pass = 0; pass < 4; pass++) {
    int r = pass * 16 + rs;
    *(uint4*)(&As[r][c * 8]) = *(const uint4*)(A + (size_t)(row0 + r) * NH + c * 8);
  }
#pragma unroll
  for (int pass = 0; pass < 8; pass++) {
    int n = pass * 16 + rs;
    *(uint4*)(&Bs[n][c * 8]) = *(const uint4*)(Wt + (size_t)n * NH + c * 8);
  }
  __syncthreads();
  int lane = t & 63, w = t >> 6;
  int m16 = lane & 15, quad = lane >> 4;
  float4v acc[8];
#pragma unroll
  for (int i = 0; i < 8; i++) acc[i] = (float4v)(0.f);
#pragma unroll
  for (int kk = 0; kk < 4; kk++) {
    short8 av = *(const short8*)(&As[w * 16 + m16][kk * 32 + quad * 8]);
#pragma unroll
    for (int ct = 0; ct < 8; ct++) {
      short8 bv = *(const short8*)(&Bs[ct * 16 + m16][kk * 32 + quad * 8]);
      acc[ct] = __builtin_amdgcn_mfma_f32_16x16x32_bf16(av, bv, acc[ct], 0, 0, 0);
    }
  }
  __syncthreads();
  // epilogue: C/D layout col=lane&15, row=quad*4+reg -> LDS bounce -> 16B stores
#pragma unroll
  for (int ct = 0; ct < 8; ct++) {
    float bv = gbias ? gbias[ct * 16 + m16] : 0.f;
#pragma unroll
    for (int r = 0; r < 4; r++) {
      As[w * 16 + quad * 4 + r][ct * 16 + m16] = f2bf(acc[ct][r] + bv);
    }
  }
  __syncthreads();
#pragma unroll
  for (int pass = 0; pass < 4; pass++) {
    int r = pass * 16 + rs;
    int gr = row0 + r;
    if (gr < NN) *(uint4*)(Y + (size_t)gr * NH + c * 8) = *(const uint4*)(&As[r][c * 8]);
  }
}

__device__ __forceinline__ void fma8(float* a, uint4 v, float cf) {
  a[0] += cf * __uint_as_float(v.x << 16);
  a[1] += cf * __uint_as_float(v.x & 0xffff0000u);
  a[2] += cf * __uint_as_float(v.y << 16);
  a[3] += cf * __uint_as_float(v.y & 0xffff0000u);
  a[4] += cf * __uint_as_float(v.z << 16);
  a[5] += cf * __uint_as_float(v.z & 0xffff0000u);
  a[6] += cf * __uint_as_float(v.w << 16);
  a[7] += cf * __uint_as_float(v.w & 0xffff0000u);
}

__device__ __forceinline__ uint4 self_pack(const float* a, uint4 sv, float d2,
                                           const float* bias, int fo) {
  float4 b0 = *(const float4*)(bias + fo);
  float4 b1 = *(const float4*)(bias + fo + 4);
  float o0 = a[0] + d2 * __uint_as_float(sv.x << 16) + b0.x;
  float o1 = a[1] + d2 * __uint_as_float(sv.x & 0xffff0000u) + b0.y;
  float o2 = a[2] + d2 * __uint_as_float(sv.y << 16) + b0.z;
  float o3 = a[3] + d2 * __uint_as_float(sv.y & 0xffff0000u) + b0.w;
  float o4 = a[4] + d2 * __uint_as_float(sv.z << 16) + b1.x;
  float o5 = a[5] + d2 * __uint_as_float(sv.z & 0xffff0000u) + b1.y;
  float o6 = a[6] + d2 * __uint_as_float(sv.w << 16) + b1.z;
  float o7 = a[7] + d2 * __uint_as_float(sv.w & 0xffff0000u) + b1.w;
  uint4 ou;
  ou.x = f2bf(o0) | ((u32)f2bf(o1) << 16);
  ou.y = f2bf(o2) | ((u32)f2bf(o3) << 16);
  ou.z = f2bf(o4) | ((u32)f2bf(o5) << 16);
  ou.w = f2bf(o6) | ((u32)f2bf(o7) << 16);
  return ou;
}

// GCN aggregate. blockIdx.y==0: chains 0&4 fused (shared set-0 edges, dual gather);
// blockIdx.y==y in 1..3: MST chain y. Wave per node; 4 edge-groups x 16 lanes x 8 bf16.
__global__ __launch_bounds__(256) void k_agg2(ZP p, const int* __restrict__ indptr,
                                              const int2* __restrict__ ent,
                                              const float* __restrict__ dinv, int4 entoff) {
  int y = blockIdx.y;
  int wv = threadIdx.x >> 6, lane = threadIdx.x & 63;
  int node = blockIdx.x * 4 + wv;
  if (node >= NN) return;
  int g = lane >> 4;
  int fo = (lane & 15) * 8;
  if (y == 0) {
    // dual: chains 0 and 4 on edge set 0 (entoff.x == 0)
    int beg = indptr[node], end = indptr[node + 1];
    const u16* __restrict__ Y0 = p.Y[0];
    const u16* __restrict__ Y4 = p.Y[4];
    float a0[8] = {0, 0, 0, 0, 0, 0, 0, 0};
    float a4[8] = {0, 0, 0, 0, 0, 0, 0, 0};
    for (int e = beg + g; e < end; e += 4) {
      int2 sc = ent[e];
      float cf = __int_as_float(sc.y);
      size_t ro = (size_t)sc.x * NH + fo;
      uint4 v0 = *(const uint4*)(Y0 + ro);
      uint4 v4 = *(const uint4*)(Y4 + ro);
      fma8(a0, v0, cf);
      fma8(a4, v4, cf);
    }
#pragma unroll
    for (int j = 0; j < 8; j++) {
      a0[j] += __shfl_xor(a0[j], 16);
      a0[j] += __shfl_xor(a0[j], 32);
      a4[j] += __shfl_xor(a4[j], 16);
      a4[j] += __shfl_xor(a4[j], 32);
    }
    if (g == 0) {
      float di = dinv[node];
      float d2 = di * di;
      size_t ro = (size_t)node * NH + fo;
      uint4 sv0 = *(const uint4*)(Y0 + ro);
      uint4 sv4 = *(const uint4*)(Y4 + ro);
      *(uint4*)(p.Xo[0] + ro) = self_pack(a0, sv0, d2, p.bias[0], fo);
      *(uint4*)(p.Xo[4] + ro) = self_pack(a4, sv4, d2, p.bias[4], fo);
    }
  } else {
    int s = y;  // set == chain for 1..3
    const int* ip = indptr + s * (NN + 1);
    int eb = (s == 1) ? entoff.y : ((s == 2) ? entoff.z : entoff.w);
    const u16* __restrict__ Y = p.Y[y];
    int beg = ip[node], end = ip[node + 1];
    const int2* __restrict__ ev = ent + eb;
    float a[8] = {0, 0, 0, 0, 0, 0, 0, 0};
    for (int e = beg + g; e < end; e += 4) {
      int2 sc = ev[e];
      float cf = __int_as_float(sc.y);
      uint4 v = *(const uint4*)(Y + (size_t)sc.x * NH + fo);
      fma8(a, v, cf);
    }
#pragma unroll
    for (int j = 0; j < 8; j++) {
      a[j] += __shfl_xor(a[j], 16);
      a[j] += __shfl_xor(a[j], 32);
    }
    if (g == 0) {
      float di = dinv[s * NN + node];
      float d2 = di * di;
      size_t ro = (size_t)node * NH + fo;
      uint4 sv = *(const uint4*)(Y + ro);
      *(uint4*)(p.Xo[y] + ro) = self_pack(a, sv, d2, p.bias[y], fo);
    }
  }
}

// stats: grid (313, NCH), 256 thr = 64 feature-pairs x 4 row-streams, u32 loads,
// flush-on-graph-change atomics (batch sorted -> <=2 graphs per 64-row window)
__global__ __launch_bounds__(256) void k_stats(ZP p, const int* __restrict__ batch,
                                               float* __restrict__ ssum, float* __restrict__ ssq) {
  int zi = blockIdx.y;
  const u16* __restrict__ X = p.Xo[zi];
  int t = threadIdx.x;
  int f2 = (t & 63) * 2, rh = t >> 6;
  int r0 = blockIdx.x * 64;
  float s0 = 0.f, s1 = 0.f, q0 = 0.f, q1 = 0.f;
  int curg = -1;
  for (int i = rh; i < 64; i += 4) {
    int r = r0 + i;
    if (r >= NN) break;
    int g = batch[r];
    if (g != curg) {
      if (curg >= 0) {
        float* su = &ssum[(size_t)(zi * NG + curg) * NH + f2];
        float* sq = &ssq[(size_t)(zi * NG + curg) * NH + f2];
        atomicAdd(su, s0); atomicAdd(su + 1, s1);
        atomicAdd(sq, q0); atomicAdd(sq + 1, q1);
      }
      curg = g; s0 = s1 = q0 = q1 = 0.f;
    }
    u32 v = *(const u32*)(X + (size_t)r * NH + f2);
    float v0 = __uint_as_float(v << 16), v1 = __uint_as_float(v & 0xffff0000u);
    s0 += v0; q0 += v0 * v0;
    s1 += v1; q1 += v1 * v1;
  }
  if (curg >= 0) {
    float* su = &ssum[(size_t)(zi * NG + curg) * NH + f2];
    float* sq = &ssq[(size_t)(zi * NG + curg) * NH + f2];
    atomicAdd(su, s0); atomicAdd(su + 1, s1);
    atomicAdd(sq, q0); atomicAdd(sq + 1, q1);
  }
}

// graph-norm + leaky -> bf16 Xn, accumulate per-graph sums into M[l] (atomics)
__global__ __launch_bounds__(256) void k_apply(ZP p, const int* __restrict__ batch,
                                               const int* __restrict__ counts,
                                               const float* __restrict__ ssum,
                                               const float* __restrict__ ssq,
                                               float* __restrict__ Ml) {
  int zi = blockIdx.y;
  const u16* __restrict__ X = p.Xo[zi];
  u16* __restrict__ Xn = p.Xn[zi];
  int t = threadIdx.x;
  int f2 = (t & 63) * 2, rh = t >> 6;
  int r0 = blockIdx.x * 64;
  float w0 = p.gw[zi][f2], w1 = p.gw[zi][f2 + 1];
  float b0 = p.gb[zi][f2], b1 = p.gb[zi][f2 + 1];
  float ms0 = p.gms[zi][f2], ms1 = p.gms[zi][f2 + 1];
  int col = p.colbase[zi] + f2;
  float m0 = 0.f, m1 = 0.f;
  int curg = -1;
  float mean0 = 0.f, mean1 = 0.f, inv0 = 0.f, inv1 = 0.f;
  for (int i = rh; i < 64; i += 4) {
    int r = r0 + i;
    if (r >= NN) break;
    int g = batch[r];
    if (g != curg) {
      if (curg >= 0) {
        atomicAdd(&Ml[(size_t)curg * 640 + col], m0);
        atomicAdd(&Ml[(size_t)curg * 640 + col + 1], m1);
      }
      m0 = m1 = 0.f;
      curg = g;
      float cnt = fmaxf((float)counts[g], 1.f);
      size_t sb = (size_t)(zi * NG + g) * NH + f2;
      mean0 = ssum[sb] / cnt;
      mean1 = ssum[sb + 1] / cnt;
      float var0 = ssq[sb] / cnt - (2.f * ms0 - ms0 * ms0) * mean0 * mean0;
      float var1 = ssq[sb + 1] / cnt - (2.f * ms1 - ms1 * ms1) * mean1 * mean1;
      inv0 = rsqrtf(var0 + GEPS);
      inv1 = rsqrtf(var1 + GEPS);
    }
    size_t ro = (size_t)r * NH + f2;
    u32 v = *(const u32*)(X + ro);
    float v0 = __uint_as_float(v << 16), v1 = __uint_as_float(v & 0xffff0000u);
    float o0 = w0 * (v0 - ms0 * mean0) * inv0 + b0;
    float o1 = w1 * (v1 - ms1 * mean1) * inv1 + b1;
    o0 = (o0 >= 0.f) ? o0 : GSLOPE * o0;
    o1 = (o1 >= 0.f) ? o1 : GSLOPE * o1;
    *(u32*)(Xn + ro) = (u32)f2bf(o0) | ((u32)f2bf(o1) << 16);
    m0 += o0; m1 += o1;
  }
  if (curg >= 0) {
    atomicAdd(&Ml[(size_t)curg * 640 + col], m0);
    atomicAdd(&Ml[(size_t)curg * 640 + col + 1], m1);
  }
}

// out[g][f] = mean_l(M[l][g][:] @ mergeW[:,f]) / cnt + mergeb[f]
__global__ __launch_bounds__(256) void k_mergeout(const float* __restrict__ M,
                                                  const float* __restrict__ mergeW,
                                                  const float* __restrict__ mergeb,
                                                  const int* __restrict__ counts,
                                                  float* __restrict__ out) {
  int g = blockIdx.x;
  int f = threadIdx.x & 127, h = threadIdx.x >> 7;
  __shared__ float mrow[640];
  __shared__ float red[128];
  float acc = 0.f;
  for (int l = 0; l < NLAY; l++) {
    const float* Mr = M + ((size_t)l * NG + g) * 640;
    for (int i = threadIdx.x; i < 640; i += 256) mrow[i] = Mr[i];
    __syncthreads();
    float s = 0.f;
    int k0 = h * 320;
#pragma unroll 8
    for (int k = k0; k < k0 + 320; k++) s += mrow[k] * mergeW[(size_t)k * NH + f];
    if (h) red[f] = s;
    __syncthreads();
    if (!h) acc += s + red[f];
    __syncthreads();
  }
  if (!h) {
    float cnt = fmaxf((float)counts[g], 1.f);
    out[(size_t)g * NH + f] = acc / (3.f * cnt) + mergeb[f];
  }
}

// ---------------- host ----------------

struct Offs {
  size_t counts, gstart, deg, M, stats, dinv, indptr, cursor, ent, wt, xbf, h0;
  size_t yb[NCH], xo[NCH], xn[NCH];
  size_t memset1_off, memset1_len, total;
};

static size_t build_offs(Offs& o, int Etot) {
  size_t off = 0;
  auto alloc = [&](size_t bytes) -> size_t {
    off = (off + 255) & ~(size_t)255;
    size_t s = off;
    off += bytes;
    return s;
  };
  o.counts = alloc(NG * 4);
  o.gstart = alloc(NG * 4);
  o.deg = alloc((size_t)4 * NN * 4);
  o.M = alloc((size_t)NLAY * NG * 640 * 4);
  // per-layer stats (ssum+ssq), all zeroed once in the startup memset
  o.stats = alloc((size_t)NLAY * 2 * NCH * NG * NH * 4);
  o.memset1_off = o.deg;
  o.memset1_len = (o.stats + (size_t)NLAY * 2 * NCH * NG * NH * 4) - o.deg;
  o.dinv = alloc((size_t)4 * NN * 4);
  o.indptr = alloc((size_t)4 * (NN + 1) * 4);
  o.cursor = alloc((size_t)4 * (NN + 1) * 4);
  o.ent = alloc((size_t)Etot * 8);
  o.wt = alloc((size_t)7 * NH * NH * 2);
  o.xbf = alloc((size_t)NNP * NH * 2);
  o.h0 = alloc((size_t)NNP * NH * 2);
  for (int i = 0; i < NCH; i++) {
    o.yb[i] = alloc((size_t)NN * NH * 2);
    o.xo[i] = alloc((size_t)NN * NH * 2);
    o.xn[i] = alloc((size_t)NNP * NH * 2);
  }
  o.total = off;
  return off;
}

extern "C" void kernel_launch(void* const* d_in, const int* in_sizes, int n_in,
                              void* d_out, int out_size, void* d_ws, size_t ws_size,
                              hipStream_t stream) {
  if (n_in < 21) return;
  const float* x = (const float*)d_in[0];
  const float* embW = (const float*)d_in[1];
  const float* embb = (const float*)d_in[2];
  const float* mainW = (const float*)d_in[3];
  const float* mainb = (const float*)d_in[4];
  const float* maingw = (const float*)d_in[5];
  const float* maingb = (const float*)d_in[6];
  const float* maingms = (const float*)d_in[7];
  const float* locW = (const float*)d_in[8];
  const float* locb = (const float*)d_in[9];
  const float* locgw = (const float*)d_in[10];
  const float* locgb = (const float*)d_in[11];
  const float* locgms = (const float*)d_in[12];
  const float* mergeW = (const float*)d_in[13];
  const float* mergeb = (const float*)d_in[14];
  const int* edge_index = (const int*)d_in[15];
  // d_in[16] = edges0: permutation of edge_index under segment_sum -> reuse set 0
  const int* edges1 = (const int*)d_in[17];
  const int* edges2 = (const int*)d_in[18];
  const int* edges3 = (const int*)d_in[19];
  const int* batch = (const int*)d_in[20];

  int E0 = in_sizes[15] / 2;
  int E1 = in_sizes[17] / 2, E2 = in_sizes[18] / 2, E3 = in_sizes[19] / 2;
  int Etot = E0 + E1 + E2 + E3;
  int maxE = E0 > E1 ? E0 : E1;
  maxE = maxE > E2 ? maxE : E2;
  maxE = maxE > E3 ? maxE : E3;

  Offs o;
  if (build_offs(o, Etot) > ws_size) return;  // fail visibly

  char* ws = (char*)d_ws;
  int* counts = (int*)(ws + o.counts);
  int* gstart = (int*)(ws + o.gstart);
  int* deg = (int*)(ws + o.deg);
  float* M = (float*)(ws + o.M);
  float* stats = (float*)(ws + o.stats);
  float* dinv = (float*)(ws + o.dinv);
  int* indptr = (int*)(ws + o.indptr);
  int* cursor = (int*)(ws + o.cursor);
  int2* ent = (int2*)(ws + o.ent);
  u16* wt = (u16*)(ws + o.wt);
  u16* xbf = (u16*)(ws + o.xbf);
  u16* h0 = (u16*)(ws + o.h0);
  u16 *yb[NCH], *xo[NCH], *xn[NCH];
  for (int i = 0; i < NCH; i++) {
    yb[i] = (u16*)(ws + o.yb[i]);
    xo[i] = (u16*)(ws + o.xo[i]);
    xn[i] = (u16*)(ws + o.xn[i]);
  }

  ES4 es;
  es.e[0] = edge_index; es.e[1] = edges1; es.e[2] = edges2; es.e[3] = edges3;
  es.cnt[0] = E0; es.cnt[1] = E1; es.cnt[2] = E2; es.cnt[3] = E3;
  es.off[0] = 0; es.off[1] = E0; es.off[2] = E0 + E1; es.off[3] = E0 + E1 + E2;
  int4 entoff = make_int4(0, E0, E0 + E1, E0 + E1 + E2);

  hipMemsetAsync(ws + o.memset1_off, 0, o.memset1_len, stream);  // deg + M + stats
  k_count2<<<1, 64, 0, stream>>>(batch, counts, gstart);
  k_deg<<<dim3((maxE + 255) / 256, 4), 256, 0, stream>>>(es, deg);
  k_scan<<<4, 1024, 0, stream>>>(deg, indptr, cursor, dinv);
  k_fill<<<dim3((maxE + 255) / 256, 4), 256, 0, stream>>>(es, dinv, cursor, ent);
  k_prepw<<<dim3(16, 7), 256, 0, stream>>>(embW, locW, mainW, wt);
  k_cast<<<(NN * NH / 8 + 255) / 256, 256, 0, stream>>>(x, xbf);

  const int nrb = (NN + 63) / 64;  // 313

  // embedding: h0 = x @ embW + embb (bf16)
  {
    ZP pe = {};
    pe.A[0] = xbf; pe.W[0] = wt; pe.Y[0] = h0;
    k_gemm_bf<<<dim3(nrb, 1), 256, 0, stream>>>(pe, embb);
  }

  const size_t statstride = (size_t)2 * NCH * NG * NH;
  for (int l = 0; l < NLAY; l++) {
    float* ssum = stats + (size_t)l * statstride;
    float* ssq = ssum + (size_t)NCH * NG * NH;
    ZP p = {};
    for (int zi = 0; zi < NCH; zi++) {
      bool isMain = (zi == 4);
      p.A[zi] = (l == 0) ? (const u16*)h0 : (const u16*)xn[zi];
      p.W[zi] = wt + (size_t)((isMain ? 4 : 1) + l) * NH * NH;
      p.Y[zi] = yb[zi];
      p.Xo[zi] = xo[zi];
      p.Xn[zi] = xn[zi];
      p.bias[zi] = (isMain ? mainb : locb) + (size_t)l * NH;
      p.gw[zi] = (isMain ? maingw : locgw) + (size_t)l * NH;
      p.gb[zi] = (isMain ? maingb : locgb) + (size_t)l * NH;
      p.gms[zi] = (isMain ? maingms : locgms) + (size_t)l * NH;
      p.set[zi] = (zi == 0 || zi == 4) ? 0 : zi;
      p.colbase[zi] = isMain ? 512 : zi * NH;
    }
    if (l == 0) {
      // chains 0..3 share A(h0) and W(locW[0]): compute once
      ZP pg = {};
      pg.A[0] = h0; pg.W[0] = wt + (size_t)1 * NH * NH; pg.Y[0] = yb[0];
      pg.A[1] = h0; pg.W[1] = wt + (size_t)4 * NH * NH; pg.Y[1] = yb[4];
      k_gemm_bf<<<dim3(nrb, 2), 256, 0, stream>>>(pg, (const float*)nullptr);
      p.Y[1] = yb[0]; p.Y[2] = yb[0]; p.Y[3] = yb[0];
    } else {
      k_gemm_bf<<<dim3(nrb, NCH), 256, 0, stream>>>(p, (const float*)nullptr);
    }
    k_agg2<<<dim3(NN / 4, 4), 256, 0, stream>>>(p, indptr, ent, dinv, entoff);
    k_stats<<<dim3(nrb, NCH), 256, 0, stream>>>(p, batch, ssum, ssq);
    k_apply<<<dim3(nrb, NCH), 256, 0, stream>>>(p, batch, counts, ssum, ssq,
                                                M + (size_t)l * NG * 640);
  }

  k_mergeout<<<NG, 256, 0, stream>>>(M, mergeW, mergeb, counts, (float*)d_out);
}